// Round 1
// baseline (83.239 us; speedup 1.0000x reference)
//
#include <hip/hip_runtime.h>
#include <math.h>

// Problem constants (fixed shapes from reference)
#define HW    16384     // H*W, B=1
#define NPIX  16384
#define NCH   128
#define NL    8
#define NDI   32

__device__ __forceinline__ float fsilu(float v) {
    return v / (1.f + __expf(-v));
}
__device__ __forceinline__ float fsoftplus(float v) {
    return (v > 20.f) ? v : log1pf(__expf(v));
}

// ---------------------------------------------------------------------------
// k1: per-pixel mamba. 256 threads = 8 pixels * 32 lanes (lane = d_inner ch).
// Writes out_hwc[pix][c] (pixel-major, coalesced) and per-block GN partials.
// All in-loop LDS deps are intra-wave -> wave_barrier only (zero cost).
// ---------------------------------------------------------------------------
__global__ __launch_bounds__(256) void k_mamba(
    const float* __restrict__ x,      // (128, 128, 128) CHW
    const float* __restrict__ Win,    // (64,16) in_proj_w
    const float* __restrict__ convw,  // (32,4)
    const float* __restrict__ convb,  // (32)
    const float* __restrict__ xpw,    // (33,32) x_proj_w
    const float* __restrict__ dtw,    // (32,1) dt_proj_w
    const float* __restrict__ dtb,    // (32) dt_proj_b
    const float* __restrict__ Alog,   // (32,16)
    const float* __restrict__ Dvec,   // (32)
    const float* __restrict__ Wout,   // (16,32)
    float* __restrict__ out_hwc,      // (NPIX,128)
    float* __restrict__ partials)     // (2048, 8): [g]=sum, [4+g]=sumsq
{
    __shared__ float s_seq[8][128];   // per-pixel input channels
    __shared__ float s_xpw[33][34];   // pad->34: odd*2 stride, 8B aligned rows
    __shared__ float s_wout[16][34];
    __shared__ float s_xs[8][32];
    __shared__ float s_bc[8][32];     // [0..15]=Bm, [16..31]=Cm
    __shared__ float s_y[8][32];
    __shared__ float s_partw[4][8];

    const int tid  = threadIdx.x;
    const int pix0 = blockIdx.x * 8;

    // stage inputs: 8 pixels * 128 channels, 32B-contiguous chunks per channel
    #pragma unroll
    for (int it = 0; it < 4; ++it) {
        int idx = it * 256 + tid;
        int pp = idx & 7, cc = idx >> 3;
        s_seq[pp][cc] = x[cc * HW + pix0 + pp];
    }
    for (int idx = tid; idx < 1056; idx += 256) s_xpw[idx >> 5][idx & 31] = xpw[idx];
    for (int idx = tid; idx < 512;  idx += 256) s_wout[idx >> 5][idx & 31] = Wout[idx];

    const int p   = tid >> 5;     // pixel within block
    const int d   = tid & 31;     // d_inner channel (lane within pixel group)
    const int pix = pix0 + p;

    // per-lane weights in registers
    float winl[16], winh[16];
    #pragma unroll
    for (int m = 0; m < 16; ++m) {
        winl[m] = Win[d * 16 + m];         // row d      -> xi
        winh[m] = Win[512 + d * 16 + m];   // row 32+d   -> z
    }
    float Arow[16];
    #pragma unroll
    for (int s = 0; s < 16; ++s) Arow[s] = -__expf(Alog[d * 16 + s]);
    const float cw0 = convw[d * 4 + 0], cw1 = convw[d * 4 + 1];
    const float cw2 = convw[d * 4 + 2], cw3 = convw[d * 4 + 3];
    const float cb  = convb[d];
    const float dtwd = dtw[d], dtbd = dtb[d], Dd = Dvec[d];

    float h[16];
    #pragma unroll
    for (int s = 0; s < 16; ++s) h[s] = 0.f;
    float w0 = 0.f, w1 = 0.f, w2 = 0.f;                 // causal conv window
    float gsum[4] = {0.f, 0.f, 0.f, 0.f};
    float gsq[4]  = {0.f, 0.f, 0.f, 0.f};

    __syncthreads();   // cross-wave: staged loads done

    #pragma unroll
    for (int l = 0; l < NL; ++l) {
        // ---- in_proj: xi = seq.Win[d], z = seq.Win[32+d]
        const float* sv = &s_seq[p][l * 16];
        float xi = 0.f, zz = 0.f;
        #pragma unroll
        for (int m = 0; m < 16; ++m) { float s0 = sv[m]; xi += s0 * winl[m]; zz += s0 * winh[m]; }

        // ---- depthwise causal conv (k=4) + silu
        float xc = cw0 * w0 + cw1 * w1 + cw2 * w2 + cw3 * xi + cb;
        w0 = w1; w1 = w2; w2 = xi;
        float xs = fsilu(xc);
        s_xs[p][d] = xs;
        __builtin_amdgcn_wave_barrier();

        // ---- x_proj: dt_raw via shuffle-reduce; lane computes dbl row d+1
        float dtr = xs * s_xpw[0][d];
        #pragma unroll
        for (int off = 16; off >= 1; off >>= 1) dtr += __shfl_xor(dtr, off);
        const float* xsv = &s_xs[p][0];
        const float* xwr = &s_xpw[d + 1][0];
        float u = 0.f;
        #pragma unroll
        for (int dd = 0; dd < 32; ++dd) u += xsv[dd] * xwr[dd];
        s_bc[p][d] = u;
        __builtin_amdgcn_wave_barrier();

        // ---- dt, selective scan step, y
        float dt = fsoftplus(dtr * dtwd + dtbd);
        float dtxs = dt * xs;
        const float* bcv = &s_bc[p][0];
        float yacc = 0.f;
        #pragma unroll
        for (int s = 0; s < 16; ++s) {
            float dA = __expf(dt * Arow[s]);
            h[s] = dA * h[s] + dtxs * bcv[s];
            yacc += h[s] * bcv[16 + s];
        }
        float yv = (yacc + xs * Dd) * fsilu(zz);
        s_y[p][d] = yv;
        __builtin_amdgcn_wave_barrier();

        // ---- out_proj: split-16 dot + one shuffle combine
        const int m = d & 15, dh = d >> 4;
        const float* yr = &s_y[p][dh * 16];
        const float* wr = &s_wout[m][dh * 16];
        float o = 0.f;
        #pragma unroll
        for (int j = 0; j < 16; ++j) o += yr[j] * wr[j];
        o += __shfl_xor(o, 16);
        if (d < 16) {
            out_hwc[pix * NCH + l * 16 + m] = o;
            gsum[l >> 1] += o;         // group = channel/32 = l/2
            gsq[l >> 1]  += o * o;
        }
        __builtin_amdgcn_wave_barrier();
    }

    // ---- block-level GN partial sums (deterministic, no atomics)
    #pragma unroll
    for (int g = 0; g < 4; ++g) {
        float a = gsum[g], b = gsq[g];
        #pragma unroll
        for (int off = 32; off >= 1; off >>= 1) {
            a += __shfl_xor(a, off);
            b += __shfl_xor(b, off);
        }
        if ((tid & 63) == 0) { s_partw[tid >> 6][g] = a; s_partw[tid >> 6][4 + g] = b; }
    }
    __syncthreads();
    if (tid < 8) {
        partials[blockIdx.x * 8 + tid] =
            s_partw[0][tid] + s_partw[1][tid] + s_partw[2][tid] + s_partw[3][tid];
    }
}

// ---------------------------------------------------------------------------
// k2: reduce 2048x8 partials -> mean[4], inv_std[4]
// ---------------------------------------------------------------------------
__global__ __launch_bounds__(256) void k_stats(
    const float* __restrict__ partials, float* __restrict__ stats)
{
    __shared__ float s_red[256];
    __shared__ float s_tot[8];
    const int tid = threadIdx.x;
    const int k = tid & 7, chunk = tid >> 3;     // 32 chunks per k
    float local = 0.f;
    for (int b = chunk; b < 2048; b += 32) local += partials[b * 8 + k];
    s_red[tid] = local;
    __syncthreads();
    if (tid < 8) {
        float t = 0.f;
        #pragma unroll
        for (int i = 0; i < 32; ++i) t += s_red[i * 8 + tid];
        s_tot[tid] = t;
    }
    __syncthreads();
    if (tid < 4) {
        const float N = 524288.f;                // 32 ch * 16384 pix
        float mean = s_tot[tid] / N;
        float var  = s_tot[4 + tid] / N - mean * mean;
        stats[tid]     = mean;
        stats[4 + tid] = rsqrtf(var + 1e-5f);
    }
}

// ---------------------------------------------------------------------------
// k3: GN apply + SiLU + residual; LDS transpose 64pix x 128ch tile so both
// the HWC read and the CHW write (+x read) are coalesced.
// ---------------------------------------------------------------------------
__global__ __launch_bounds__(256) void k_apply(
    const float* __restrict__ out_hwc,
    const float* __restrict__ x,
    const float* __restrict__ stats,
    const float* __restrict__ gamma,
    const float* __restrict__ beta,
    float* __restrict__ outp)
{
    __shared__ float s_t[64][129];               // +1 pad: conflict-free col read
    const int tid  = threadIdx.x;
    const int pix0 = blockIdx.x * 64;

    #pragma unroll
    for (int it = 0; it < 32; ++it) {
        int idx = it * 256 + tid;
        int cc = idx & 127, pp = idx >> 7;
        s_t[pp][cc] = out_hwc[pix0 * NCH + idx];  // fully coalesced
    }
    float mu0 = stats[0], mu1 = stats[1], mu2 = stats[2], mu3 = stats[3];
    float iv0 = stats[4], iv1 = stats[5], iv2 = stats[6], iv3 = stats[7];
    __syncthreads();

    #pragma unroll
    for (int it = 0; it < 32; ++it) {
        int idx = it * 256 + tid;
        int pp = idx & 63, cc = idx >> 6;
        int g = cc >> 5;
        float mu = (g & 2) ? ((g & 1) ? mu3 : mu2) : ((g & 1) ? mu1 : mu0);
        float iv = (g & 2) ? ((g & 1) ? iv3 : iv2) : ((g & 1) ? iv1 : iv0);
        float v  = s_t[pp][cc];
        float a  = (v - mu) * iv * gamma[cc] + beta[cc];
        int o = cc * HW + pix0 + pp;
        outp[o] = x[o] + fsilu(a);
    }
}

// ---------------------------------------------------------------------------
extern "C" void kernel_launch(void* const* d_in, const int* in_sizes, int n_in,
                              void* d_out, int out_size, void* d_ws, size_t ws_size,
                              hipStream_t stream)
{
    const float* x     = (const float*)d_in[0];
    const float* Win   = (const float*)d_in[1];
    const float* convw = (const float*)d_in[2];
    const float* convb = (const float*)d_in[3];
    const float* xpw   = (const float*)d_in[4];
    const float* dtw   = (const float*)d_in[5];
    const float* dtb   = (const float*)d_in[6];
    const float* Alog  = (const float*)d_in[7];
    const float* Dvec  = (const float*)d_in[8];
    const float* Wout  = (const float*)d_in[9];
    const float* gamma = (const float*)d_in[10];
    const float* beta  = (const float*)d_in[11];
    float* outp = (float*)d_out;

    // workspace layout (floats): [0,2M) out_hwc, [2M,2M+16K) partials, then stats
    float* ws       = (float*)d_ws;
    float* out_hwc  = ws;
    float* partials = ws + 2097152;
    float* stats    = ws + 2097152 + 16384;
    // requires ~8.46 MB of workspace

    k_mamba<<<dim3(2048), dim3(256), 0, stream>>>(
        x, Win, convw, convb, xpw, dtw, dtb, Alog, Dvec, Wout, out_hwc, partials);
    k_stats<<<dim3(1), dim3(256), 0, stream>>>(partials, stats);
    k_apply<<<dim3(256), dim3(256), 0, stream>>>(out_hwc, x, stats, gamma, beta, outp);
}

// Round 3
// 76.546 us; speedup vs baseline: 1.0874x; 1.0874x over previous
//
#include <hip/hip_runtime.h>
#include <math.h>

// Problem constants (fixed shapes from reference)
#define HW    16384     // H*W, B=1
#define NCH   128

__device__ __forceinline__ float fsilu(float v) {
    return __fdividef(v, 1.f + __expf(-v));
}

// ---------------------------------------------------------------------------
// k1: per-pixel mamba, phase-batched. 256 threads = 8 pixels * 32 lanes,
// 2 pixel-batches per block (16 pixels). Lane = d_inner channel.
// Phases: A (in_proj+conv+silu for all 8 l) -> B (x_proj: lane d owns dbl
// row d+1; dt_raw redundantly per lane from broadcast row 0) -> C (scan) ->
// D (out_proj: lane owns channels d+32k). All cross-lane LDS traffic is
// intra-32-lane-group -> wave_barrier only.
// ---------------------------------------------------------------------------
__global__ __launch_bounds__(256) void k_mamba(
    const float* __restrict__ x,      // (128,128,128) CHW
    const float* __restrict__ Win,    // (64,16)
    const float* __restrict__ convw,  // (32,4)
    const float* __restrict__ convb,  // (32)
    const float* __restrict__ xpw,    // (33,32)
    const float* __restrict__ dtw,    // (32,1)
    const float* __restrict__ dtb,    // (32)
    const float* __restrict__ Alog,   // (32,16)
    const float* __restrict__ Dvec,   // (32)
    const float* __restrict__ Wout,   // (16,32)
    float* __restrict__ out_hwc,      // (16384,128)
    float* __restrict__ partials)     // (1024,8)
{
    __shared__ float s_seq[16][128];  // staged input, full 64B lines of x
    __shared__ float s_xpw0[32];      // x_proj row 0 (dt_raw weights)
    __shared__ float s_xpwB[32][36];  // rows 1..32, pad 36 (16B-aligned rows)
    __shared__ float s_wout[16][36];
    __shared__ float s_xs[8][8][32];  // [p][l][d]
    __shared__ float s_bc[8][8][32];  // [p][l][row-1]: 0..15=B, 16..31=C
    __shared__ float s_y [8][8][32];
    __shared__ float s_partw[4][8];

    const int tid  = threadIdx.x;
    const int pix0 = blockIdx.x * 16;

    // stage x: 16 pixels * 128 channels = 2048 elems (8 iters of 256)
    #pragma unroll
    for (int it = 0; it < 8; ++it) {
        int idx = it * 256 + tid;
        int pp = idx & 15, cc = idx >> 4;
        s_seq[pp][cc] = x[cc * HW + pix0 + pp];   // 16 consecutive lanes = 64B line
    }
    for (int idx = tid; idx < 1024; idx += 256) s_xpwB[idx >> 5][idx & 31] = xpw[32 + idx];
    if (tid < 32) s_xpw0[tid] = xpw[tid];
    for (int idx = tid; idx < 512;  idx += 256) s_wout[idx >> 5][idx & 31] = Wout[idx];

    const int p = tid >> 5;      // pixel-in-batch
    const int d = tid & 31;      // d_inner channel

    // per-lane weights (vectorized global loads, L2/L3-resident)
    float winl[16], winh[16];
    const float4* W4 = (const float4*)Win;
    #pragma unroll
    for (int q = 0; q < 4; ++q) {
        float4 v = W4[d * 4 + q];
        winl[q*4+0] = v.x; winl[q*4+1] = v.y; winl[q*4+2] = v.z; winl[q*4+3] = v.w;
        float4 w = W4[128 + d * 4 + q];
        winh[q*4+0] = w.x; winh[q*4+1] = w.y; winh[q*4+2] = w.z; winh[q*4+3] = w.w;
    }
    float Arow[16];              // -exp(Alog)*log2(e): dA = exp2(dt*Arow)
    const float4* A4 = (const float4*)Alog;
    #pragma unroll
    for (int q = 0; q < 4; ++q) {
        float4 v = A4[d * 4 + q];
        Arow[q*4+0] = -__expf(v.x) * 1.44269504f;
        Arow[q*4+1] = -__expf(v.y) * 1.44269504f;
        Arow[q*4+2] = -__expf(v.z) * 1.44269504f;
        Arow[q*4+3] = -__expf(v.w) * 1.44269504f;
    }
    const float4 cwv = ((const float4*)convw)[d];
    const float cb   = convb[d];
    const float dtwd = dtw[d], dtbd = dtb[d], Dd = Dvec[d];

    float gsum[4] = {0.f,0.f,0.f,0.f};
    float gsq[4]  = {0.f,0.f,0.f,0.f};

    __syncthreads();   // staging visible block-wide

    #pragma unroll
    for (int bat = 0; bat < 2; ++bat) {
        const int pl  = bat * 8 + p;
        const int pix = pix0 + pl;

        // ---- Phase A: in_proj (xi, z) for all l, conv+silu -> xs
        float xi[8], zz[8];
        const float4* sp4 = (const float4*)&s_seq[pl][0];
        #pragma unroll
        for (int l = 0; l < 8; ++l) {
            float a = 0.f, b = 0.f;
            #pragma unroll
            for (int q = 0; q < 4; ++q) {
                float4 v = sp4[l * 4 + q];   // broadcast b128
                a += v.x*winl[q*4] + v.y*winl[q*4+1] + v.z*winl[q*4+2] + v.w*winl[q*4+3];
                b += v.x*winh[q*4] + v.y*winh[q*4+1] + v.z*winh[q*4+2] + v.w*winh[q*4+3];
            }
            xi[l] = a; zz[l] = b;
        }
        float xs[8];
        #pragma unroll
        for (int l = 0; l < 8; ++l) {
            float c0 = (l >= 3) ? xi[l-3] : 0.f;
            float c1 = (l >= 2) ? xi[l-2] : 0.f;
            float c2 = (l >= 1) ? xi[l-1] : 0.f;
            float t  = cwv.x*c0 + cwv.y*c1 + cwv.z*c2 + cwv.w*xi[l] + cb;
            xs[l] = fsilu(t);
            s_xs[p][l][d] = xs[l];           // bank = d, conflict-free
        }
        __builtin_amdgcn_wave_barrier();

        // ---- Phase B: u[l] = dbl row d+1; dtr[l] = dt_raw (all lanes)
        float u[8]   = {0.f,0.f,0.f,0.f,0.f,0.f,0.f,0.f};
        float dtr[8] = {0.f,0.f,0.f,0.f,0.f,0.f,0.f,0.f};
        const float4* xw4 = (const float4*)&s_xpwB[d][0];
        const float4* x04 = (const float4*)&s_xpw0[0];
        #pragma unroll
        for (int q = 0; q < 8; ++q) {
            float4 w  = xw4[q];              // per-lane row
            float4 w0 = x04[q];              // broadcast
            #pragma unroll
            for (int l = 0; l < 8; ++l) {
                float4 xv = ((const float4*)&s_xs[p][l][0])[q];   // broadcast
                u[l]   += xv.x*w.x  + xv.y*w.y  + xv.z*w.z  + xv.w*w.w;
                dtr[l] += xv.x*w0.x + xv.y*w0.y + xv.z*w0.z + xv.w*w0.w;
            }
        }
        #pragma unroll
        for (int l = 0; l < 8; ++l) s_bc[p][l][d] = u[l];
        __builtin_amdgcn_wave_barrier();

        // ---- Phase C: softplus(dt), selective scan
        float h[16];
        #pragma unroll
        for (int s = 0; s < 16; ++s) h[s] = 0.f;
        #pragma unroll
        for (int l = 0; l < 8; ++l) {
            float t  = dtr[l] * dtwd + dtbd;
            float e  = __expf(t);
            float dt = (t > 20.f) ? t : __logf(1.f + e);
            float Bv[16], Cv[16];
            const float4* bc4 = (const float4*)&s_bc[p][l][0];    // broadcast
            #pragma unroll
            for (int q = 0; q < 4; ++q) {
                *(float4*)&Bv[q*4] = bc4[q];
                *(float4*)&Cv[q*4] = bc4[4 + q];
            }
            float dtxs = dt * xs[l];
            float yacc = 0.f;
            #pragma unroll
            for (int s = 0; s < 16; ++s) {
                float dA = exp2f(dt * Arow[s]);
                h[s] = dA * h[s] + dtxs * Bv[s];
                yacc += h[s] * Cv[s];
            }
            float yv = (yacc + xs[l] * Dd) * fsilu(zz[l]);
            s_y[p][l][d] = yv;               // bank = d, conflict-free
        }
        __builtin_amdgcn_wave_barrier();

        // ---- Phase D: out_proj; lane owns channels c = d + 32k
        const int mrow  = d & 15;
        const int lbase = d >> 4;
        const float4* wo4 = (const float4*)&s_wout[mrow][0];
        #pragma unroll
        for (int k = 0; k < 4; ++k) {
            int l = lbase + 2 * k;           // token index for channel d+32k
            const float4* y4 = (const float4*)&s_y[p][l][0];      // 2-addr broadcast
            float o = 0.f;
            #pragma unroll
            for (int q = 0; q < 8; ++q) {
                float4 yv = y4[q];
                float4 w  = wo4[q];
                o += yv.x*w.x + yv.y*w.y + yv.z*w.z + yv.w*w.w;
            }
            out_hwc[pix * NCH + d + 32 * k] = o;   // coalesced 128B chunks
            gsum[k] += o;                          // channel group == k
            gsq[k]  += o * o;
        }
        __builtin_amdgcn_wave_barrier();
    }

    // ---- block GN partials (deterministic)
    #pragma unroll
    for (int g = 0; g < 4; ++g) {
        float a = gsum[g], b = gsq[g];
        #pragma unroll
        for (int off = 32; off >= 1; off >>= 1) {
            a += __shfl_xor(a, off);
            b += __shfl_xor(b, off);
        }
        if ((tid & 63) == 0) { s_partw[tid >> 6][g] = a; s_partw[tid >> 6][4 + g] = b; }
    }
    __syncthreads();
    if (tid < 8) {
        partials[blockIdx.x * 8 + tid] =
            s_partw[0][tid] + s_partw[1][tid] + s_partw[2][tid] + s_partw[3][tid];
    }
}

// ---------------------------------------------------------------------------
// k2: reduce 1024x8 partials -> mean[4], inv_std[4]
// ---------------------------------------------------------------------------
__global__ __launch_bounds__(256) void k_stats(
    const float* __restrict__ partials, float* __restrict__ stats)
{
    __shared__ float s_red[256];
    __shared__ float s_tot[8];
    const int tid = threadIdx.x;
    const int k = tid & 7, chunk = tid >> 3;
    float local = 0.f;
    for (int b = chunk; b < 1024; b += 32) local += partials[b * 8 + k];
    s_red[tid] = local;
    __syncthreads();
    if (tid < 8) {
        float t = 0.f;
        #pragma unroll
        for (int i = 0; i < 32; ++i) t += s_red[i * 8 + tid];
        s_tot[tid] = t;
    }
    __syncthreads();
    if (tid < 4) {
        const float N = 524288.f;            // 32 ch * 16384 pix
        float mean = s_tot[tid] / N;
        float var  = s_tot[4 + tid] / N - mean * mean;
        stats[tid]     = mean;
        stats[4 + tid] = rsqrtf(var + 1e-5f);
    }
}

// ---------------------------------------------------------------------------
// k3: GN apply + SiLU + residual; LDS transpose 64pix x 128ch tile
// ---------------------------------------------------------------------------
__global__ __launch_bounds__(256) void k_apply(
    const float* __restrict__ out_hwc,
    const float* __restrict__ x,
    const float* __restrict__ stats,
    const float* __restrict__ gamma,
    const float* __restrict__ beta,
    float* __restrict__ outp)
{
    __shared__ float s_t[64][129];
    const int tid  = threadIdx.x;
    const int pix0 = blockIdx.x * 64;

    #pragma unroll
    for (int it = 0; it < 32; ++it) {
        int idx = it * 256 + tid;
        int cc = idx & 127, pp = idx >> 7;
        s_t[pp][cc] = out_hwc[pix0 * NCH + idx];
    }
    float mu0 = stats[0], mu1 = stats[1], mu2 = stats[2], mu3 = stats[3];
    float iv0 = stats[4], iv1 = stats[5], iv2 = stats[6], iv3 = stats[7];
    __syncthreads();

    #pragma unroll
    for (int it = 0; it < 32; ++it) {
        int idx = it * 256 + tid;
        int pp = idx & 63, cc = idx >> 6;
        int g = cc >> 5;
        float mu = (g & 2) ? ((g & 1) ? mu3 : mu2) : ((g & 1) ? mu1 : mu0);
        float iv = (g & 2) ? ((g & 1) ? iv3 : iv2) : ((g & 1) ? iv1 : iv0);
        float v  = s_t[pp][cc];
        float a  = (v - mu) * iv * gamma[cc] + beta[cc];
        int o = cc * HW + pix0 + pp;
        outp[o] = x[o] + fsilu(a);
    }
}

// ---------------------------------------------------------------------------
extern "C" void kernel_launch(void* const* d_in, const int* in_sizes, int n_in,
                              void* d_out, int out_size, void* d_ws, size_t ws_size,
                              hipStream_t stream)
{
    const float* x     = (const float*)d_in[0];
    const float* Win   = (const float*)d_in[1];
    const float* convw = (const float*)d_in[2];
    const float* convb = (const float*)d_in[3];
    const float* xpw   = (const float*)d_in[4];
    const float* dtw   = (const float*)d_in[5];
    const float* dtb   = (const float*)d_in[6];
    const float* Alog  = (const float*)d_in[7];
    const float* Dvec  = (const float*)d_in[8];
    const float* Wout  = (const float*)d_in[9];
    const float* gamma = (const float*)d_in[10];
    const float* beta  = (const float*)d_in[11];
    float* outp = (float*)d_out;

    float* ws       = (float*)d_ws;
    float* out_hwc  = ws;
    float* partials = ws + 2097152;
    float* stats    = ws + 2097152 + 16384;

    k_mamba<<<dim3(1024), dim3(256), 0, stream>>>(
        x, Win, convw, convb, xpw, dtw, dtb, Alog, Dvec, Wout, out_hwc, partials);
    k_stats<<<dim3(1), dim3(256), 0, stream>>>(partials, stats);
    k_apply<<<dim3(256), dim3(256), 0, stream>>>(out_hwc, x, stats, gamma, beta, outp);
}